// Round 4
// baseline (541.296 us; speedup 1.0000x reference)
//
#include <hip/hip_runtime.h>
#include <hip/hip_bf16.h>
#include <cstdint>
#include <cstddef>

// B=4, NQ=NK=2048, E=1024, H=16, HD=64, INT=1024.
// Established interface: inputs f32 (r0 NaN evidence), output f32 (r2/r3
// misalignment signature: independent impls agreed at absmax 0.2744/0.2749 =
// bf16-written-into-f32-buffer read skew). Ref is bf16-quantized, thr = 2%.
typedef __bf16 bf16_t;
typedef __bf16 bf16x8 __attribute__((ext_vector_type(8)));
typedef float f32x4 __attribute__((ext_vector_type(4)));

#define EDIM 1024
#define HH 16
#define HD 64
#define NSEQ 2048

// async global->LDS, 16B per lane. LDS dest must be wave-uniform base + lane*16.
__device__ __forceinline__ void async_copy16(const bf16_t* gsrc, bf16_t* lds_dst) {
    __builtin_amdgcn_global_load_lds(
        (const __attribute__((address_space(1))) uint32_t*)gsrc,
        (__attribute__((address_space(3))) uint32_t*)lds_dst,
        16, 0, 0);
}

// ---------------------------------------------------------------------------
// Weight transpose + bf16 convert: W (1024x1024, KxN, f32) -> WT (NxK, bf16).
// ---------------------------------------------------------------------------
__global__ void transpose_all(const float* __restrict__ w0, const float* __restrict__ w1,
                              const float* __restrict__ w2, const float* __restrict__ w3,
                              bf16_t* __restrict__ o0, bf16_t* __restrict__ o1,
                              bf16_t* __restrict__ o2, bf16_t* __restrict__ o3) {
    __shared__ bf16_t t[64][65];
    const float* in;
    bf16_t* out;
    switch (blockIdx.z) {
        case 0: in = w0; out = o0; break;
        case 1: in = w1; out = o1; break;
        case 2: in = w2; out = o2; break;
        default: in = w3; out = o3; break;
    }
    const int tid = threadIdx.x;
    const int kt = blockIdx.x, nt = blockIdx.y;
    #pragma unroll
    for (int i = 0; i < 16; i++) {
        int idx = i * 256 + tid;
        int r = idx >> 6, c = idx & 63;
        t[r][c] = (bf16_t)in[(size_t)(kt * 64 + r) * 1024 + nt * 64 + c];
    }
    __syncthreads();
    #pragma unroll
    for (int i = 0; i < 16; i++) {
        int idx = i * 256 + tid;
        int r = idx >> 6, c = idx & 63;
        out[(size_t)(nt * 64 + r) * 1024 + kt * 64 + c] = t[c][r];
    }
}

// ---------------------------------------------------------------------------
// NT GEMM: C(MxN) = A(MxK) * Bt(NxK)^T + bias. 128x128 tile, BK=32.
// AB=0: A f32 (convert to bf16 during staging). AB=1: A bf16 (async copy).
// Bt: bf16 (pre-transposed weights). bias: f32.
// MODE 0: write C head-major [b][h][n][d] bf16   (Q, K projections)
// MODE 1: write C transposed [b][h][d][n] bf16   (V projection)
// MODE 2: plain row-major MxN, dtype OUT         (output projection, f32)
// ---------------------------------------------------------------------------
template <int AB, int MODE, typename OUT>
__global__ __launch_bounds__(256, 2)
void gemm_nt(const void* __restrict__ Araw, const bf16_t* __restrict__ Bt,
             const float* __restrict__ bias, OUT* __restrict__ C,
             int M, int N, int K) {
    constexpr int BM = 128, BN = 128, BK = 32;
    __shared__ bf16_t Asm[BM * BK];  // row-major (m, k)
    __shared__ bf16_t Bsm[BN * BK];  // row-major (n, k)
    const int tid = threadIdx.x;
    const int wave = tid >> 6, lane = tid & 63;
    const int quad = lane >> 4, l15 = lane & 15;
    const int m0 = blockIdx.x * BM;
    const int n0 = blockIdx.y * BN;
    const int wm = (wave & 1) * 64, wn = (wave >> 1) * 64;

    f32x4 acc[4][4] = {};

    for (int k0 = 0; k0 < K; k0 += BK) {
        __syncthreads();
        if (AB) {
            const bf16_t* A = (const bf16_t*)Araw;
            #pragma unroll
            for (int i = 0; i < 2; i++) {
                int chunk = i * 256 + tid;       // 512 chunks x 8 elems = 128x32
                int row = chunk >> 2, kc = chunk & 3;
                async_copy16(A + (size_t)(m0 + row) * K + k0 + kc * 8, Asm + chunk * 8);
            }
        } else {
            const float* A = (const float*)Araw;
            #pragma unroll
            for (int i = 0; i < 2; i++) {
                int chunk = i * 256 + tid;
                int row = chunk >> 2, kc = chunk & 3;
                const float* s = A + (size_t)(m0 + row) * K + k0 + kc * 8;
                float4 x = *(const float4*)s;
                float4 y = *(const float4*)(s + 4);
                bf16x8 vv = {(bf16_t)x.x, (bf16_t)x.y, (bf16_t)x.z, (bf16_t)x.w,
                             (bf16_t)y.x, (bf16_t)y.y, (bf16_t)y.z, (bf16_t)y.w};
                *(bf16x8*)&Asm[chunk * 8] = vv;
            }
        }
        #pragma unroll
        for (int i = 0; i < 2; i++) {
            int chunk = i * 256 + tid;
            int row = chunk >> 2, kc = chunk & 3;
            async_copy16(Bt + (size_t)(n0 + row) * K + k0 + kc * 8, Bsm + chunk * 8);
        }
        __syncthreads();

        bf16x8 af[4], bfr[4];
        #pragma unroll
        for (int mi = 0; mi < 4; mi++)
            af[mi] = *(const bf16x8*)&Asm[(wm + mi * 16 + l15) * BK + quad * 8];
        #pragma unroll
        for (int ni = 0; ni < 4; ni++)
            bfr[ni] = *(const bf16x8*)&Bsm[(wn + ni * 16 + l15) * BK + quad * 8];
        #pragma unroll
        for (int mi = 0; mi < 4; mi++)
            #pragma unroll
            for (int ni = 0; ni < 4; ni++)
                acc[mi][ni] = __builtin_amdgcn_mfma_f32_16x16x32_bf16(
                    af[mi], bfr[ni], acc[mi][ni], 0, 0, 0);
    }

    // Epilogue. C/D layout: row = quad*4 + r, col = l15 (verified m89/m91).
    #pragma unroll
    for (int mi = 0; mi < 4; mi++) {
        #pragma unroll
        for (int ni = 0; ni < 4; ni++) {
            #pragma unroll
            for (int r = 0; r < 4; r++) {
                int m = m0 + wm + mi * 16 + quad * 4 + r;
                int nch = n0 + wn + ni * 16 + l15;
                float v = acc[mi][ni][r] + bias[nch];
                if (MODE == 2) {
                    C[(size_t)m * N + nch] = (OUT)v;
                } else {
                    int b = m >> 11, n = m & 2047;
                    int h = nch >> 6, d = nch & 63;
                    if (MODE == 0)
                        C[(((size_t)(b * HH + h)) * NSEQ + n) * HD + d] = (OUT)v;
                    else
                        C[(((size_t)(b * HH + h)) * HD + d) * NSEQ + n] = (OUT)v;
                }
            }
        }
    }
}

// ---------------------------------------------------------------------------
// Flash attention: grid (NQ/128, B*H). 256 threads = 4 waves; wave w owns
// q-rows [w*32, w*32+32). kv-tile = 64. Online softmax, per-wave-exclusive rows.
// Qh, Kh: [bh][n][d] bf16. Vt: [bh][d][n] bf16. Out ao: [b][n][INT] bf16.
// ---------------------------------------------------------------------------
__global__ __launch_bounds__(256, 2)
void attn_kernel(const bf16_t* __restrict__ Qh, const bf16_t* __restrict__ Kh,
                 const bf16_t* __restrict__ Vt, bf16_t* __restrict__ out) {
    __shared__ bf16_t Qs[128 * 64];   // 16 KB  (n, d)
    __shared__ bf16_t Ks[64 * 64];    //  8 KB  (kv, d)
    __shared__ bf16_t Vs[64 * 64];    //  8 KB  (d, kv)
    __shared__ bf16_t Ps[128 * 64];   // 16 KB  (q, kv)
    const int tid = threadIdx.x, wave = tid >> 6, lane = tid & 63;
    const int quad = lane >> 4, l15 = lane & 15;
    const int qtile = blockIdx.x, bh = blockIdx.y;
    const int b = bh >> 4, h = bh & 15;

    const bf16_t* qbase = Qh + ((size_t)bh * NSEQ + qtile * 128) * HD;
    const bf16_t* kbase = Kh + (size_t)bh * NSEQ * HD;
    const bf16_t* vbase = Vt + (size_t)bh * HD * NSEQ;

    // Stage Q tile once: contiguous 128*64 slab.
    #pragma unroll
    for (int i = 0; i < 4; i++) {
        int chunk = i * 256 + tid;
        async_copy16(qbase + (size_t)chunk * 8, Qs + chunk * 8);
    }

    float m_prev[2][4], l_prev[2][4];
    #pragma unroll
    for (int mi = 0; mi < 2; mi++)
        #pragma unroll
        for (int r = 0; r < 4; r++) { m_prev[mi][r] = -1e30f; l_prev[mi][r] = 0.f; }
    f32x4 oacc[2][4] = {};

    const float scale = 0.125f;  // 1/sqrt(64)

    for (int t = 0; t < 32; t++) {
        __syncthreads();  // prior iter's Ks/Vs reads done; drains outstanding copies
        #pragma unroll
        for (int i = 0; i < 2; i++) {  // K tile: contiguous slab 64*64
            int chunk = i * 256 + tid;
            async_copy16(kbase + (size_t)t * 64 * HD + chunk * 8, Ks + chunk * 8);
        }
        #pragma unroll
        for (int i = 0; i < 2; i++) {  // V^T tile: row d contiguous in n
            int chunk = i * 256 + tid;
            int d = chunk >> 3, nc = chunk & 7;
            async_copy16(vbase + (size_t)d * NSEQ + t * 64 + nc * 8, Vs + chunk * 8);
        }
        __syncthreads();

        // S = Q K^T (this wave's 32 rows x 64 kv)
        f32x4 sacc[2][4] = {};
        #pragma unroll
        for (int ks = 0; ks < 2; ks++) {
            bf16x8 aq[2];
            #pragma unroll
            for (int mi = 0; mi < 2; mi++)
                aq[mi] = *(const bf16x8*)&Qs[(wave * 32 + mi * 16 + l15) * 64 + ks * 32 + quad * 8];
            #pragma unroll
            for (int ni = 0; ni < 4; ni++) {
                bf16x8 bk = *(const bf16x8*)&Ks[(ni * 16 + l15) * 64 + ks * 32 + quad * 8];
                #pragma unroll
                for (int mi = 0; mi < 2; mi++)
                    sacc[mi][ni] = __builtin_amdgcn_mfma_f32_16x16x32_bf16(
                        aq[mi], bk, sacc[mi][ni], 0, 0, 0);
            }
        }

        // Online softmax; row = quad*4 + r; reduce across the 16 lanes of the quad.
        #pragma unroll
        for (int mi = 0; mi < 2; mi++) {
            #pragma unroll
            for (int r = 0; r < 4; r++) {
                float mx = -1e30f;
                #pragma unroll
                for (int ni = 0; ni < 4; ni++) mx = fmaxf(mx, sacc[mi][ni][r]);
                mx *= scale;
                #pragma unroll
                for (int off = 1; off < 16; off <<= 1) mx = fmaxf(mx, __shfl_xor(mx, off, 64));
                float mnew = fmaxf(m_prev[mi][r], mx);
                float alpha = __expf(m_prev[mi][r] - mnew);
                float rs = 0.f;
                #pragma unroll
                for (int ni = 0; ni < 4; ni++) {
                    float p = __expf(sacc[mi][ni][r] * scale - mnew);
                    rs += p;
                    Ps[(wave * 32 + mi * 16 + quad * 4 + r) * 64 + ni * 16 + l15] = (bf16_t)p;
                }
                #pragma unroll
                for (int off = 1; off < 16; off <<= 1) rs += __shfl_xor(rs, off, 64);
                l_prev[mi][r] = l_prev[mi][r] * alpha + rs;
                m_prev[mi][r] = mnew;
                #pragma unroll
                for (int di = 0; di < 4; di++) oacc[mi][di][r] *= alpha;
            }
        }
        __syncthreads();  // P C-layout -> A-layout via LDS

        // O += P V
        #pragma unroll
        for (int ks = 0; ks < 2; ks++) {
            bf16x8 ap[2];
            #pragma unroll
            for (int mi = 0; mi < 2; mi++)
                ap[mi] = *(const bf16x8*)&Ps[(wave * 32 + mi * 16 + l15) * 64 + ks * 32 + quad * 8];
            #pragma unroll
            for (int di = 0; di < 4; di++) {
                bf16x8 bv = *(const bf16x8*)&Vs[(di * 16 + l15) * 64 + ks * 32 + quad * 8];
                #pragma unroll
                for (int mi = 0; mi < 2; mi++)
                    oacc[mi][di] = __builtin_amdgcn_mfma_f32_16x16x32_bf16(
                        ap[mi], bv, oacc[mi][di], 0, 0, 0);
            }
        }
    }

    // Epilogue: O / l -> attn_out [b][n][h*64+d] bf16
    #pragma unroll
    for (int mi = 0; mi < 2; mi++)
        #pragma unroll
        for (int di = 0; di < 4; di++)
            #pragma unroll
            for (int r = 0; r < 4; r++) {
                int n = qtile * 128 + wave * 32 + mi * 16 + quad * 4 + r;
                int c = h * 64 + di * 16 + l15;
                float v = oacc[mi][di][r] / l_prev[mi][r];
                out[((size_t)b * NSEQ + n) * EDIM + c] = (bf16_t)v;
            }
}

// ---------------------------------------------------------------------------
extern "C" void kernel_launch(void* const* d_in, const int* in_sizes, int n_in,
                              void* d_out, int out_size, void* d_ws, size_t ws_size,
                              hipStream_t stream) {
    const float* q  = (const float*)d_in[0];
    const float* k  = (const float*)d_in[1];
    const float* v  = (const float*)d_in[2];
    const float* wq = (const float*)d_in[3];
    const float* bq = (const float*)d_in[4];
    const float* wk = (const float*)d_in[5];
    const float* bk = (const float*)d_in[6];
    const float* wv = (const float*)d_in[7];
    const float* bv = (const float*)d_in[8];
    const float* wo = (const float*)d_in[9];
    const float* bo = (const float*)d_in[10];
    float* out = (float*)d_out;   // reference output dtype = float32

    char* ws = (char*)d_ws;
    bf16_t* wqt = (bf16_t*)(ws + ((size_t)0  << 20)); // 2 MB each, bf16 NxK
    bf16_t* wkt = (bf16_t*)(ws + ((size_t)2  << 20));
    bf16_t* wvt = (bf16_t*)(ws + ((size_t)4  << 20));
    bf16_t* wot = (bf16_t*)(ws + ((size_t)6  << 20));
    bf16_t* Qh  = (bf16_t*)(ws + ((size_t)8  << 20)); // 16 MB [b][h][n][d]
    bf16_t* Kh  = (bf16_t*)(ws + ((size_t)24 << 20)); // 16 MB [b][h][n][d]
    bf16_t* Vt  = (bf16_t*)(ws + ((size_t)40 << 20)); // 16 MB [b][h][d][n]
    bf16_t* ao  = (bf16_t*)(ws + ((size_t)56 << 20)); // 16 MB [b][n][INT]

    dim3 tb(256);

    transpose_all<<<dim3(16, 16, 4), tb, 0, stream>>>(wq, wk, wv, wo, wqt, wkt, wvt, wot);

    dim3 gg(64, 8);  // M=8192/128, N=1024/128
    gemm_nt<0, 0, bf16_t><<<gg, tb, 0, stream>>>(q, wqt, bq, Qh, 8192, 1024, 1024);
    gemm_nt<0, 0, bf16_t><<<gg, tb, 0, stream>>>(k, wkt, bk, Kh, 8192, 1024, 1024);
    gemm_nt<0, 1, bf16_t><<<gg, tb, 0, stream>>>(v, wvt, bv, Vt, 8192, 1024, 1024);

    attn_kernel<<<dim3(16, 64), tb, 0, stream>>>(Qh, Kh, Vt, ao);

    gemm_nt<1, 2, float><<<gg, tb, 0, stream>>>(ao, wot, bo, out, 8192, 1024, 1024);
}